// Round 1
// baseline (36791.949 us; speedup 1.0000x reference)
//
#include <hip/hip_runtime.h>
#include <hip/hip_cooperative_groups.h>
#include <cmath>

namespace cg = cooperative_groups;

#define BATCH 128
#define TLEN  256
#define HDIM  1024
#define CDIM  10
#define JPW   4              // hidden units per workgroup
#define NWG   (HDIM / JPW)   // 256 workgroups, 1 per CU
#define NT    256            // threads per workgroup
#define KC    64             // k-chunk staged in LDS

// h state, double buffered, k-major: g_h[buf][j][b]
__device__ float g_h[2][HDIM][BATCH];

__global__ void __launch_bounds__(NT, 1)
lstm_persistent(const float* __restrict__ x,
                const float* __restrict__ Wgx, const float* __restrict__ Wgh, const float* __restrict__ bg,
                const float* __restrict__ Wix, const float* __restrict__ Wih, const float* __restrict__ bi,
                const float* __restrict__ Wfx, const float* __restrict__ Wfh, const float* __restrict__ bf,
                const float* __restrict__ Wox, const float* __restrict__ Woh, const float* __restrict__ bo,
                const float* __restrict__ Wph, const float* __restrict__ bp,
                float* __restrict__ out)
{
    // LDS: 64 KB weights + 2x32 KB h staging = 128 KB (<160 KB)
    __shared__ float Wl[16][HDIM];        // [jj*4 + gate][k]
    __shared__ float hs[2][KC][BATCH];

    const int tid = threadIdx.x;
    const int b   = tid & (BATCH - 1);    // batch column (2 threads per b)
    const int sub = tid >> 7;             // 0: jl 0..1, 1: jl 2..3
    const int jbase = blockIdx.x * JPW;

    const float* Wh[4] = {Wgh, Wih, Wfh, Woh};
    const float* Wx[4] = {Wgx, Wix, Wfx, Wox};
    const float* Bs[4] = {bg, bi, bf, bo};

    // ---- load this WG's 16 gate-weight rows into LDS (coalesced float4) ----
    #pragma unroll
    for (int r = 0; r < 16; ++r) {
        const int jj = r >> 2, gate = r & 3;
        const float4* src = (const float4*)(Wh[gate] + (size_t)(jbase + jj) * HDIM);
        float4* dst = (float4*)&Wl[r][0];
        dst[tid] = src[tid];              // HDIM/4 == NT
    }

    // per-thread x-weights and biases for (2 j) x (4 gates)
    float wxr[2][4], bir[2][4];
    #pragma unroll
    for (int jl = 0; jl < 2; ++jl) {
        const int j = jbase + sub * 2 + jl;
        #pragma unroll
        for (int gate = 0; gate < 4; ++gate) {
            wxr[jl][gate] = Wx[gate][j];
            bir[jl][gate] = Bs[gate][j];
        }
    }

    // zero h0 (this WG's rows); c in registers
    for (int i = tid; i < JPW * BATCH; i += NT)
        g_h[0][jbase + i / BATCH][i % BATCH] = 0.f;
    float c0 = 0.f, c1 = 0.f;

    cg::grid_group grid = cg::this_grid();
    __syncthreads();
    __threadfence();
    grid.sync();

    const int wbase = sub * 8;

    for (int t = 0; t < TLEN; ++t) {
        const float* hb = &g_h[t & 1][0][0];
        float*       hn = &g_h[(t + 1) & 1][0][0];

        float acc[8];
        #pragma unroll
        for (int rr = 0; rr < 8; ++rr) acc[rr] = 0.f;

        const float4* gsrc = (const float4*)hb;
        float4 pf[8];
        #pragma unroll
        for (int i = 0; i < 8; ++i) pf[i] = gsrc[tid + i * NT];

        for (int ch = 0; ch < HDIM / KC; ++ch) {
            const int cur = ch & 1;
            float4* hdst = (float4*)&hs[cur][0][0];
            #pragma unroll
            for (int i = 0; i < 8; ++i) hdst[tid + i * NT] = pf[i];
            __syncthreads();

            if (ch + 1 < HDIM / KC) {
                const float4* s = gsrc + (ch + 1) * (KC * BATCH / 4);
                #pragma unroll
                for (int i = 0; i < 8; ++i) pf[i] = s[tid + i * NT];
            }

            const int kbase = ch * KC;
            #pragma unroll 4
            for (int kk = 0; kk < KC; kk += 4) {
                const float h0 = hs[cur][kk + 0][b];
                const float h1 = hs[cur][kk + 1][b];
                const float h2 = hs[cur][kk + 2][b];
                const float h3 = hs[cur][kk + 3][b];
                #pragma unroll
                for (int rr = 0; rr < 8; ++rr) {
                    const float4 w = *(const float4*)&Wl[wbase + rr][kbase + kk];
                    float a = acc[rr];
                    a = fmaf(h0, w.x, a);
                    a = fmaf(h1, w.y, a);
                    a = fmaf(h2, w.z, a);
                    a = fmaf(h3, w.w, a);
                    acc[rr] = a;
                }
            }
            // single barrier per chunk: protects hs[cur] reuse two chunks later
        }

        // ---- epilogue: gates, c/h update, write h ----
        const float xt = x[(size_t)b * TLEN + t];
        #pragma unroll
        for (int jl = 0; jl < 2; ++jl) {
            const float pg = acc[jl * 4 + 0] + xt * wxr[jl][0] + bir[jl][0];
            const float pi = acc[jl * 4 + 1] + xt * wxr[jl][1] + bir[jl][1];
            const float pf_ = acc[jl * 4 + 2] + xt * wxr[jl][2] + bir[jl][2];
            const float po = acc[jl * 4 + 3] + xt * wxr[jl][3] + bir[jl][3];
            const float gg = tanhf(pg);
            const float ii = 1.f / (1.f + expf(-pi));
            const float ff = 1.f / (1.f + expf(-pf_));
            const float oo = 1.f / (1.f + expf(-po));
            float cc = (jl == 0) ? c0 : c1;
            cc = gg * ii + cc * ff;
            if (jl == 0) c0 = cc; else c1 = cc;
            const float hv = tanhf(cc) * oo;
            hn[(size_t)(jbase + sub * 2 + jl) * BATCH + b] = hv;
        }

        __threadfence();
        grid.sync();
    }

    // ---- final projection: out = h @ W_ph + bias_p (final h is in buffer 0) ----
    if (blockIdx.x < BATCH) {
        const int bp_ = blockIdx.x;
        float part[CDIM];
        #pragma unroll
        for (int cc = 0; cc < CDIM; ++cc) part[cc] = 0.f;
        for (int k = tid; k < HDIM; k += NT) {
            const float hv = g_h[0][k][bp_];
            #pragma unroll
            for (int cc = 0; cc < CDIM; ++cc)
                part[cc] += hv * Wph[(size_t)k * CDIM + cc];
        }
        float* red = (float*)&hs[0][0][0];   // reuse staging LDS: 256*12*4 = 12 KB
        #pragma unroll
        for (int cc = 0; cc < CDIM; ++cc) red[tid * 12 + cc] = part[cc];
        __syncthreads();
        for (int s = NT / 2; s > 0; s >>= 1) {
            if (tid < s) {
                #pragma unroll
                for (int cc = 0; cc < CDIM; ++cc)
                    red[tid * 12 + cc] += red[(tid + s) * 12 + cc];
            }
            __syncthreads();
        }
        if (tid < CDIM) out[(size_t)bp_ * CDIM + tid] = red[tid] + bp[tid];
    }
}

extern "C" void kernel_launch(void* const* d_in, const int* in_sizes, int n_in,
                              void* d_out, int out_size, void* d_ws, size_t ws_size,
                              hipStream_t stream) {
    const float* x   = (const float*)d_in[0];
    const float* Wgx = (const float*)d_in[1];
    const float* Wgh = (const float*)d_in[2];
    const float* bg  = (const float*)d_in[3];
    const float* Wix = (const float*)d_in[4];
    const float* Wih = (const float*)d_in[5];
    const float* bi  = (const float*)d_in[6];
    const float* Wfx = (const float*)d_in[7];
    const float* Wfh = (const float*)d_in[8];
    const float* bf  = (const float*)d_in[9];
    const float* Wox = (const float*)d_in[10];
    const float* Woh = (const float*)d_in[11];
    const float* bo  = (const float*)d_in[12];
    const float* Wph = (const float*)d_in[13];
    const float* bp  = (const float*)d_in[14];
    float* out = (float*)d_out;

    void* args[] = {&x, &Wgx, &Wgh, &bg, &Wix, &Wih, &bi, &Wfx, &Wfh, &bf,
                    &Wox, &Woh, &bo, &Wph, &bp, &out};
    hipLaunchCooperativeKernel((void*)lstm_persistent, dim3(NWG), dim3(NT),
                               args, 0, stream);
}